// Round 14
// baseline (4943.722 us; speedup 1.0000x reference)
//
#include <hip/hip_runtime.h>
#include <hip/hip_bf16.h>
#include <math.h>

typedef __attribute__((ext_vector_type(4))) float vf4;
typedef __attribute__((ext_vector_type(4))) unsigned int vu4;
typedef __attribute__((ext_vector_type(8))) short vbf8;
typedef __attribute__((ext_vector_type(8))) unsigned short vus8;

#define NWG   128
#define NTHR  256
#define LEN   1024
#define H3    3072
#define CND   80
#define EMBD  128

// ---- ws byte offsets ----
#define TAB1_B  0ull
#define TAB2_B  (TAB1_B + 786432ull*4)
#define TAB3_B  (TAB2_B + 786432ull*4)
#define BF_B    (TAB3_B + 786432ull*4)            // bfrag: 128oct*2which*35frag*512 bf16
#define MELA_B  (BF_B   + 4587520ull*2)           // melA : 1024t*2m*3frag*512 bf16
#define AF_B    (MELA_B + 3145728ull*2)           // Afrag: 1025t*64frag*512 bf16
#define CNT_B   (AF_B   + 33587200ull*2)          // (unused)
#define W1F_B   (CNT_B + 4096ull)                 // O1w frags
#define W2F_B   (W1F_B + 1179648ull)
#define W3F_B   (W2F_B + 393216ull)
#define W4F_B   (W3F_B + 131072ull)
#define FOFS    8388608ull                        // flogits offset in d_out

// ============================ prep kernels (r13 verbatim) ============================

__global__ __launch_bounds__(256) void make_tables(const float* __restrict__ IW,
                                                   const float* __restrict__ Ib,
                                                   const float* __restrict__ cemb,
                                                   const float* __restrict__ femb,
                                                   float* __restrict__ tab1,
                                                   float* __restrict__ tab2,
                                                   float* __restrict__ tab3) {
    int blk = blockIdx.x;
    int table = blk / 3072;
    int rem = blk % 3072;
    int row = rem / 12;
    int cc = rem % 12;
    int col = cc * 256 + threadIdx.x;
    int ofs = CND + table * EMBD;
    const float* emb = (table == 1) ? femb : cemb;
    float acc = 0.f;
    for (int k = 0; k < EMBD; ++k)
        acc += emb[row * EMBD + k] * IW[(size_t)(ofs + k) * H3 + col];
    if (table == 0) acc += Ib[col];
    if (table == 2 && ((col & 1023) < 768)) acc = 0.f;
    float* dst = (table == 0) ? tab1 : (table == 1 ? tab2 : tab3);
    dst[(size_t)row * H3 + col] = acc;
}

__global__ __launch_bounds__(256) void build_bfrag2(const float* __restrict__ Rw,
                                                    const float* __restrict__ IW,
                                                    const float* __restrict__ Rb,
                                                    unsigned short* __restrict__ Bf) {
    int idx = blockIdx.x * 256 + threadIdx.x;     // k*3072 + col, k in 0..1119
    int col = idx % 3072;
    int k   = idx / 3072;
    float v;
    if (k < 1024)       v = Rw[(size_t)k * H3 + col];
    else if (k < 1104)  v = IW[(size_t)(k - 1024) * H3 + col];
    else if (k == 1104) v = Rb[col];
    else return;

    int g  = col >> 10;
    int j  = col & 1023;
    int oct = j >> 3, jo = j & 7;
    int which, c;
    if (g < 2)      { which = 0; c = g * 8 + jo; }
    else {
        which = 1;
        if (k < 1024 || k == 1104) c = jo;
        else                        c = 8 + jo;
    }
    int kk = k >> 5, r5 = k & 31;
    int lane = (r5 >> 3) * 16 + c;
    int elem = r5 & 7;
    size_t dst = (((size_t)oct * 2 + which) * 35 + kk) * 512 + lane * 8 + elem;
    __hip_bfloat16 hb = __float2bfloat16(v);
    Bf[dst] = *(unsigned short*)&hb;
}

__global__ __launch_bounds__(256) void build_melA(const float* __restrict__ mel,
                                                  unsigned short* __restrict__ MelA) {
    long idx = (long)blockIdx.x * 256 + threadIdx.x;
    int elem = idx & 7;
    int lane = (idx >> 3) & 63;
    int kkm  = (int)((idx >> 9) % 3);
    int m    = (int)((idx / 1536) & 1);
    int t    = (int)(idx / 3072);
    int b    = m * 16 + (lane & 15);
    int km   = kkm * 32 + ((lane >> 4) & 3) * 8 + elem;
    float v = (km < CND) ? mel[((size_t)b * LEN + t) * CND + km] : (km == CND ? 1.f : 0.f);
    __hip_bfloat16 hb = __float2bfloat16(v);
    MelA[idx] = *(unsigned short*)&hb;
}

__global__ __launch_bounds__(256) void build_wfrag(const float* __restrict__ W,
                                                   unsigned short* __restrict__ Wf,
                                                   int K, int N) {
    int idx = blockIdx.x * 256 + threadIdx.x;
    if (idx >= K * N) return;
    int col = idx % N;
    int k   = idx / N;
    int nt = col >> 4, c = col & 15;
    int kf = k >> 5, k5 = k & 31;
    int lane = c + 16 * (k5 >> 3);
    int elem = k5 & 7;
    size_t dst = ((size_t)nt * (K >> 5) + kf) * 512 + (size_t)lane * 8 + elem;
    __hip_bfloat16 hb = __float2bfloat16(W[idx]);
    Wf[dst] = *(unsigned short*)&hb;
}

// ============================ persistent scan: sentinel dataflow, wide pull ============================
// r13's barrier-free scheme with the pull re-done as 16x global_load_dwordx4
// sc0 sc1 (coherence-point reads, 16B/op -- half the op count of u64 atomics)
// issued in one asm block; table gathers + mel MFMA overlap the load flight;
// s_waitcnt block with "+v" ties prevents early consumption. Retry on sentinel.
#define CK4(v) (((v)[0]==0xFFFFFFFFu)|((v)[1]==0xFFFFFFFFu)|((v)[2]==0xFFFFFFFFu)|((v)[3]==0xFFFFFFFFu))

#define ISSUE16()                                                                  \
    asm volatile(                                                                  \
        "global_load_dwordx4 %[o0],  %[a0], off sc0 sc1\n\t"                       \
        "global_load_dwordx4 %[o1],  %[a0], off offset:1024 sc0 sc1\n\t"           \
        "global_load_dwordx4 %[o2],  %[a0], off offset:2048 sc0 sc1\n\t"           \
        "global_load_dwordx4 %[o3],  %[a0], off offset:3072 sc0 sc1\n\t"           \
        "global_load_dwordx4 %[o4],  %[a1], off sc0 sc1\n\t"                       \
        "global_load_dwordx4 %[o5],  %[a1], off offset:1024 sc0 sc1\n\t"           \
        "global_load_dwordx4 %[o6],  %[a1], off offset:2048 sc0 sc1\n\t"           \
        "global_load_dwordx4 %[o7],  %[a1], off offset:3072 sc0 sc1\n\t"           \
        "global_load_dwordx4 %[o8],  %[a2], off sc0 sc1\n\t"                       \
        "global_load_dwordx4 %[o9],  %[a2], off offset:1024 sc0 sc1\n\t"           \
        "global_load_dwordx4 %[o10], %[a2], off offset:2048 sc0 sc1\n\t"           \
        "global_load_dwordx4 %[o11], %[a2], off offset:3072 sc0 sc1\n\t"           \
        "global_load_dwordx4 %[o12], %[a3], off sc0 sc1\n\t"                       \
        "global_load_dwordx4 %[o13], %[a3], off offset:1024 sc0 sc1\n\t"           \
        "global_load_dwordx4 %[o14], %[a3], off offset:2048 sc0 sc1\n\t"           \
        "global_load_dwordx4 %[o15], %[a3], off offset:3072 sc0 sc1"               \
        : [o0]"=&v"(q0),  [o1]"=&v"(q1),  [o2]"=&v"(q2),  [o3]"=&v"(q3),           \
          [o4]"=&v"(q4),  [o5]"=&v"(q5),  [o6]"=&v"(q6),  [o7]"=&v"(q7),           \
          [o8]"=&v"(q8),  [o9]"=&v"(q9),  [o10]"=&v"(q10),[o11]"=&v"(q11),         \
          [o12]"=&v"(q12),[o13]"=&v"(q13),[o14]"=&v"(q14),[o15]"=&v"(q15)          \
        : [a0]"v"(a0), [a1]"v"(a1), [a2]"v"(a2), [a3]"v"(a3)                       \
        : "memory")

#define WAIT16()                                                                   \
    asm volatile("s_waitcnt vmcnt(0)"                                              \
        : [o0]"+v"(q0),  [o1]"+v"(q1),  [o2]"+v"(q2),  [o3]"+v"(q3),               \
          [o4]"+v"(q4),  [o5]"+v"(q5),  [o6]"+v"(q6),  [o7]"+v"(q7),               \
          [o8]"+v"(q8),  [o9]"+v"(q9),  [o10]"+v"(q10),[o11]"+v"(q11),             \
          [o12]"+v"(q12),[o13]"+v"(q13),[o14]"+v"(q14),[o15]"+v"(q15)              \
        :: "memory")

__global__ __launch_bounds__(256, 1) void scan_persist(const unsigned short* __restrict__ Bf,
                                                       const unsigned short* __restrict__ MelA,
                                                       unsigned short* __restrict__ Af,
                                                       const float* __restrict__ tab1,
                                                       const float* __restrict__ tab2,
                                                       const float* __restrict__ tab3,
                                                       const int* __restrict__ xin) {
    __shared__ __align__(16) unsigned short Bs[2 * 35 * 512];     // 71,680 B
    __shared__ __align__(16) unsigned short hstage[64 * 512];     // 65,536 B
    __shared__ float ex[32][36];                                  //  4,608 B

    int tid = threadIdx.x;
    int wg  = blockIdx.x;
    int lane = tid & 63;
    int wv = tid >> 6;            // 0..3
    int m  = wv >> 1;             // A half (batch 0-15 / 16-31)
    int n  = wv & 1;              // 0: [u|r] cols, 1: [e1|e2] cols

    // ---- stage this WG's B fragments into LDS (one-time) ----
    {
        const unsigned int* src = (const unsigned int*)(Bf + (size_t)wg * (2 * 35 * 512));
        unsigned int* dst = (unsigned int*)Bs;
#pragma unroll
        for (int i = 0; i < 70; ++i) dst[tid + i * 256] = src[tid + i * 256];
    }
    __syncthreads();

    // gate role: one (b, j) per thread
    int gb = tid >> 3, gjl = tid & 7;
    int gj = wg * 8 + gjl;
    float hreg = 0.f;
    size_t wbase = (size_t)(((gb >> 4) * 32 + (gj >> 5)) * 512 +
                            ((gb & 15) + 16 * ((gj >> 3) & 3)) * 8 + (gj & 7));

    const unsigned short* Bn = Bs + (n * 35) * 512 + lane * 8;

#pragma unroll 1
    for (int t = 0; t < LEN; ++t) {
        // ---- issue the 16-frag coherent pull of this wave's Af[t] slice ----
        vu4 q0, q1, q2, q3, q4, q5, q6, q7, q8, q9, q10, q11, q12, q13, q14, q15;
        const unsigned short* pb = Af + (size_t)t * 32768 + (size_t)(wv * 16) * 512 + lane * 8;
        unsigned long long a0 = (unsigned long long)pb;
        unsigned long long a1 = (unsigned long long)(pb + 4 * 512);
        unsigned long long a2 = (unsigned long long)(pb + 8 * 512);
        unsigned long long a3 = (unsigned long long)(pb + 12 * 512);
        ISSUE16();

        // ---- overlap window: table gathers + mel MFMA (independent of h[t]) ----
        int ci = xin[(gb * LEN + t) * 2];
        int fi = xin[(gb * LEN + t) * 2 + 1];
        int cn = xin[(gb * LEN + ((t + 1) & (LEN - 1))) * 2];
        float t1u = tab1[(size_t)ci * H3 + gj];
        float t2u = tab2[(size_t)fi * H3 + gj];
        float t3u = tab3[(size_t)cn * H3 + gj];
        float t1r = tab1[(size_t)ci * H3 + 1024 + gj];
        float t2r = tab2[(size_t)fi * H3 + 1024 + gj];
        float t3r = tab3[(size_t)cn * H3 + 1024 + gj];
        float t1e = tab1[(size_t)ci * H3 + 2048 + gj];
        float t2e = tab2[(size_t)fi * H3 + 2048 + gj];
        float t3e = tab3[(size_t)cn * H3 + 2048 + gj];

        const unsigned short* Am = MelA + (size_t)t * 3072 + (size_t)(m * 3) * 512 + lane * 8;
        vf4 amel = {0.f, 0.f, 0.f, 0.f};
#pragma unroll
        for (int kq = 0; kq < 3; ++kq) {
            vbf8 a = *(const vbf8*)(Am + kq * 512);
            vbf8 b = *(const vbf8*)(Bn + (32 + kq) * 512);
            amel = __builtin_amdgcn_mfma_f32_16x16x32_bf16(a, b, amel, 0, 0, 0);
        }

        // ---- wait + sentinel retry ----
        WAIT16();
        int bad = CK4(q0) | CK4(q1) | CK4(q2) | CK4(q3) | CK4(q4) | CK4(q5) |
                  CK4(q6) | CK4(q7) | CK4(q8) | CK4(q9) | CK4(q10) | CK4(q11) |
                  CK4(q12) | CK4(q13) | CK4(q14) | CK4(q15);
        while (__any(bad)) {
            __builtin_amdgcn_s_sleep(1);
            ISSUE16();
            WAIT16();
            bad = CK4(q0) | CK4(q1) | CK4(q2) | CK4(q3) | CK4(q4) | CK4(q5) |
                  CK4(q6) | CK4(q7) | CK4(q8) | CK4(q9) | CK4(q10) | CK4(q11) |
                  CK4(q12) | CK4(q13) | CK4(q14) | CK4(q15);
        }

        // ---- stash slice into hstage ----
        {
            unsigned short* hd = hstage + (size_t)(wv * 16) * 512 + lane * 8;
            *(vu4*)(hd + 0 * 512)  = q0;  *(vu4*)(hd + 1 * 512)  = q1;
            *(vu4*)(hd + 2 * 512)  = q2;  *(vu4*)(hd + 3 * 512)  = q3;
            *(vu4*)(hd + 4 * 512)  = q4;  *(vu4*)(hd + 5 * 512)  = q5;
            *(vu4*)(hd + 6 * 512)  = q6;  *(vu4*)(hd + 7 * 512)  = q7;
            *(vu4*)(hd + 8 * 512)  = q8;  *(vu4*)(hd + 9 * 512)  = q9;
            *(vu4*)(hd + 10 * 512) = q10; *(vu4*)(hd + 11 * 512) = q11;
            *(vu4*)(hd + 12 * 512) = q12; *(vu4*)(hd + 13 * 512) = q13;
            *(vu4*)(hd + 14 * 512) = q14; *(vu4*)(hd + 15 * 512) = q15;
        }
        __syncthreads();   // hstage complete

        // ---- D(16x16) = A(16x1120) x B(1120x16): A,B from LDS ----
        const unsigned short* Ah = hstage + (size_t)(m * 32) * 512 + lane * 8;
        vf4 acc0 = amel, acc1 = {0.f, 0.f, 0.f, 0.f};
#pragma unroll
        for (int kk = 0; kk < 32; kk += 2) {
            vbf8 a0v = *(const vbf8*)(Ah + kk * 512);
            vbf8 b0v = *(const vbf8*)(Bn + kk * 512);
            acc0 = __builtin_amdgcn_mfma_f32_16x16x32_bf16(a0v, b0v, acc0, 0, 0, 0);
            vbf8 a1v = *(const vbf8*)(Ah + (kk + 1) * 512);
            vbf8 b1v = *(const vbf8*)(Bn + (kk + 1) * 512);
            acc1 = __builtin_amdgcn_mfma_f32_16x16x32_bf16(a1v, b1v, acc1, 0, 0, 0);
        }
        vf4 acc = acc0 + acc1;

        // ---- exchange pre-activations (C: col=lane&15, row=(lane>>4)*4+r) ----
#pragma unroll
        for (int r = 0; r < 4; ++r)
            ex[m * 16 + ((lane >> 4) * 4 + r)][n * 16 + (lane & 15)] = acc[r];
        __syncthreads();

        // ---- gates + state update ----
        float gu  = ex[gb][gjl]      + t1u + t2u + t3u;
        float gr  = ex[gb][8 + gjl]  + t1r + t2r + t3r;
        float e1  = ex[gb][16 + gjl];
        float ge2 = ex[gb][24 + gjl] + t1e + t2e + t3e;
        float u  = 1.f / (1.f + expf(-gu));
        float r_ = 1.f / (1.f + expf(-gr));
        float e  = tanhf(r_ * e1 + ge2);
        hreg = u * hreg + (1.f - u) * e;

        // ---- fire-and-forget packed h store (pair via shfl) ----
        __hip_bfloat16 hb = __float2bfloat16(hreg);
        int myv = (int)(*(unsigned short*)&hb);
        int nbv = __shfl_xor(myv, 1);
        if ((tid & 1) == 0) {
            unsigned int pk = ((unsigned)myv & 0xffffu) | ((unsigned)nbv << 16);
            __hip_atomic_store((unsigned int*)(Af + (size_t)(t + 1) * 32768 + wbase), pk,
                               __ATOMIC_RELAXED, __HIP_MEMORY_SCOPE_AGENT);
        }
        // no drain, no arrival, no fence -- consumers sentinel-poll the data.
    }
}

// ============================ MFMA output MLPs (r12 verbatim) ============================
__global__ __launch_bounds__(512) void out_mlp_mfma(
        const unsigned short* __restrict__ Af,
        const unsigned short* __restrict__ W1f, const float* __restrict__ O1b,
        const unsigned short* __restrict__ W2f, const float* __restrict__ O2b,
        const unsigned short* __restrict__ W3f, const float* __restrict__ O3b,
        const unsigned short* __restrict__ W4f, const float* __restrict__ O4b,
        float* __restrict__ out) {
    __shared__ __align__(16) unsigned short Zc[2 * 24 * 512];   // 48 KB
    __shared__ __align__(16) unsigned short Zf[2 * 8 * 512];    // 16 KB

    int tid = threadIdx.x;
    int lane = tid & 63;
    int wv = tid >> 6;
    int m = wv >> 2;
    int q = wv & 3;
    int l = blockIdx.x;
    int c16 = lane & 15;
    int rowq = lane >> 4;

    const unsigned short* Abase = Af + (size_t)(l + 1) * 32768 +
                                  (size_t)(m * 32) * 512 + (size_t)lane * 8;

    {
        vf4 acc[12];
#pragma unroll
        for (int i = 0; i < 12; ++i) acc[i] = (vf4){0.f, 0.f, 0.f, 0.f};
        for (int kk = 0; kk < 24; ++kk) {
            vbf8 a = *(const vbf8*)(Abase + kk * 512);
#pragma unroll
            for (int i = 0; i < 12; ++i) {
                int nt = q * 12 + i;
                vbf8 b = *(const vbf8*)(W1f + ((size_t)nt * 24 + kk) * 512 + lane * 8);
                acc[i] = __builtin_amdgcn_mfma_f32_16x16x32_bf16(a, b, acc[i], 0, 0, 0);
            }
        }
#pragma unroll
        for (int i = 0; i < 12; ++i) {
            int nt = q * 12 + i;
            int col = nt * 16 + c16;
            float bias = O1b[col];
#pragma unroll
            for (int r = 0; r < 4; ++r) {
                float v = fmaxf(acc[i][r] + bias, 0.f);
                __hip_bfloat16 hb = __float2bfloat16(v);
                int my = (int)*(unsigned short*)&hb;
                int nb = __shfl_xor(my, 1);
                if ((lane & 1) == 0) {
                    unsigned pk = ((unsigned)my & 0xffffu) | ((unsigned)nb << 16);
                    int row = rowq * 4 + r;
                    int kk2 = col >> 5, k5 = col & 31;
                    int lp = row + 16 * (k5 >> 3);
                    int ep = k5 & 7;
                    *(unsigned*)&Zc[(size_t)(m * 24 + kk2) * 512 + lp * 8 + ep] = pk;
                }
            }
        }
    }
    __syncthreads();

    {
        vf4 acc[4];
#pragma unroll
        for (int i = 0; i < 4; ++i) acc[i] = (vf4){0.f, 0.f, 0.f, 0.f};
        for (int kk = 0; kk < 24; ++kk) {
            vbf8 a = *(const vbf8*)(Zc + (size_t)(m * 24 + kk) * 512 + lane * 8);
#pragma unroll
            for (int i = 0; i < 4; ++i) {
                int nt = q * 4 + i;
                vbf8 b = *(const vbf8*)(W2f + ((size_t)nt * 24 + kk) * 512 + lane * 8);
                acc[i] = __builtin_amdgcn_mfma_f32_16x16x32_bf16(a, b, acc[i], 0, 0, 0);
            }
        }
#pragma unroll
        for (int i = 0; i < 4; ++i) {
            int nt = q * 4 + i;
            int col = nt * 16 + c16;
            float bias = O2b[col];
#pragma unroll
            for (int r = 0; r < 4; ++r) {
                int nn = m * 16 + rowq * 4 + r;
                out[((size_t)nn * 1024 + l) * 256 + col] = acc[i][r] + bias;
            }
        }
    }

    {
        vf4 acc[4];
#pragma unroll
        for (int i = 0; i < 4; ++i) acc[i] = (vf4){0.f, 0.f, 0.f, 0.f};
        for (int kf = 0; kf < 8; ++kf) {
            vbf8 a = *(const vbf8*)(Abase + (24 + kf) * 512);
#pragma unroll
            for (int i = 0; i < 4; ++i) {
                int nt = q * 4 + i;
                vbf8 b = *(const vbf8*)(W3f + ((size_t)nt * 8 + kf) * 512 + lane * 8);
                acc[i] = __builtin_amdgcn_mfma_f32_16x16x32_bf16(a, b, acc[i], 0, 0, 0);
            }
        }
#pragma unroll
        for (int i = 0; i < 4; ++i) {
            int nt = q * 4 + i;
            int col = nt * 16 + c16;
            float bias = O3b[col];
#pragma unroll
            for (int r = 0; r < 4; ++r) {
                float v = fmaxf(acc[i][r] + bias, 0.f);
                __hip_bfloat16 hb = __float2bfloat16(v);
                int my = (int)*(unsigned short*)&hb;
                int nb = __shfl_xor(my, 1);
                if ((lane & 1) == 0) {
                    unsigned pk = ((unsigned)my & 0xffffu) | ((unsigned)nb << 16);
                    int row = rowq * 4 + r;
                    int kk2 = col >> 5, k5 = col & 31;
                    int lp = row + 16 * (k5 >> 3);
                    int ep = k5 & 7;
                    *(unsigned*)&Zf[(size_t)(m * 8 + kk2) * 512 + lp * 8 + ep] = pk;
                }
            }
        }
    }
    __syncthreads();

    {
        vf4 acc[4];
#pragma unroll
        for (int i = 0; i < 4; ++i) acc[i] = (vf4){0.f, 0.f, 0.f, 0.f};
        for (int kf = 0; kf < 8; ++kf) {
            vbf8 a = *(const vbf8*)(Zf + (size_t)(m * 8 + kf) * 512 + lane * 8);
#pragma unroll
            for (int i = 0; i < 4; ++i) {
                int nt = q * 4 + i;
                vbf8 b = *(const vbf8*)(W4f + ((size_t)nt * 8 + kf) * 512 + lane * 8);
                acc[i] = __builtin_amdgcn_mfma_f32_16x16x32_bf16(a, b, acc[i], 0, 0, 0);
            }
        }
#pragma unroll
        for (int i = 0; i < 4; ++i) {
            int nt = q * 4 + i;
            int col = nt * 16 + c16;
            float bias = O4b[col];
#pragma unroll
            for (int r = 0; r < 4; ++r) {
                int nn = m * 16 + rowq * 4 + r;
                out[FOFS + ((size_t)nn * 1024 + l) * 256 + col] = acc[i][r] + bias;
            }
        }
    }
}

// ============================ launch ============================
extern "C" void kernel_launch(void* const* d_in, const int* in_sizes, int n_in,
                              void* d_out, int out_size, void* d_ws, size_t ws_size,
                              hipStream_t stream) {
    const int*   x    = (const int*)d_in[0];
    const float* mel  = (const float*)d_in[1];
    const float* Rw   = (const float*)d_in[2];
    const float* Rb   = (const float*)d_in[3];
    const float* IW   = (const float*)d_in[4];
    const float* Ib   = (const float*)d_in[5];
    const float* O1w  = (const float*)d_in[6];
    const float* O1b  = (const float*)d_in[7];
    const float* O2w  = (const float*)d_in[8];
    const float* O2b  = (const float*)d_in[9];
    const float* O3w  = (const float*)d_in[10];
    const float* O3b  = (const float*)d_in[11];
    const float* O4w  = (const float*)d_in[12];
    const float* O4b  = (const float*)d_in[13];
    const float* cemb = (const float*)d_in[14];
    const float* femb = (const float*)d_in[15];
    char* wsb = (char*)d_ws;
    float* out = (float*)d_out;

    float* tab1 = (float*)(wsb + TAB1_B);
    float* tab2 = (float*)(wsb + TAB2_B);
    float* tab3 = (float*)(wsb + TAB3_B);
    unsigned short* Bf   = (unsigned short*)(wsb + BF_B);
    unsigned short* MelA = (unsigned short*)(wsb + MELA_B);
    unsigned short* Af   = (unsigned short*)(wsb + AF_B);
    unsigned short* W1f  = (unsigned short*)(wsb + W1F_B);
    unsigned short* W2f  = (unsigned short*)(wsb + W2F_B);
    unsigned short* W3f  = (unsigned short*)(wsb + W3F_B);
    unsigned short* W4f  = (unsigned short*)(wsb + W4F_B);

    make_tables<<<9216, 256, 0, stream>>>(IW, Ib, cemb, femb, tab1, tab2, tab3);
    hipMemsetAsync((void*)Bf, 0, 4587520ull * 2, stream);
    build_bfrag2<<<13440, 256, 0, stream>>>(Rw, IW, Rb, Bf);
    build_melA<<<12288, 256, 0, stream>>>(mel, MelA);
    build_wfrag<<<2304, 256, 0, stream>>>(O1w, W1f, 768, 768);
    build_wfrag<<<768,  256, 0, stream>>>(O2w, W2f, 768, 256);
    build_wfrag<<<256,  256, 0, stream>>>(O3w, W3f, 256, 256);
    build_wfrag<<<256,  256, 0, stream>>>(O4w, W4f, 256, 256);
    hipMemsetAsync((void*)Af, 0xFF, 33587200ull * 2, stream);   // sentinel-seed all slots
    hipMemsetAsync((void*)Af, 0, 65536, stream);                // h0 = 0 (slot 0 readable)

    scan_persist<<<NWG, NTHR, 0, stream>>>(Bf, MelA, Af, tab1, tab2, tab3, x);

    out_mlp_mfma<<<1024, 512, 0, stream>>>(Af, W1f, O1b, W2f, O2b, W3f, O3b, W4f, O4b, out);
}

// Round 15
// 4095.621 us; speedup vs baseline: 1.2071x; 1.2071x over previous
//
#include <hip/hip_runtime.h>
#include <hip/hip_bf16.h>
#include <math.h>

typedef __attribute__((ext_vector_type(4))) float vf4;
typedef __attribute__((ext_vector_type(8))) short vbf8;
typedef __attribute__((ext_vector_type(8))) unsigned short vus8;

#define NWG   128
#define NTHR  256
#define LEN   1024
#define H3    3072
#define CND   80
#define EMBD  128

// ---- ws byte offsets ----
#define TAB1_B  0ull
#define TAB2_B  (TAB1_B + 786432ull*4)
#define TAB3_B  (TAB2_B + 786432ull*4)
#define BF_B    (TAB3_B + 786432ull*4)            // bfrag: 128oct*2which*35frag*512 bf16
#define MELA_B  (BF_B   + 4587520ull*2)           // melA : 1024t*2m*3frag*512 bf16
#define AF_B    (MELA_B + 3145728ull*2)           // Afrag: 1025t*64frag*512 bf16
#define CNT_B   (AF_B   + 33587200ull*2)          // (unused)
#define W1F_B   (CNT_B + 4096ull)                 // O1w frags
#define W2F_B   (W1F_B + 1179648ull)
#define W3F_B   (W2F_B + 393216ull)
#define W4F_B   (W3F_B + 131072ull)
#define FOFS    8388608ull                        // flogits offset in d_out

// ============================ prep kernels (r13 verbatim) ============================

__global__ __launch_bounds__(256) void make_tables(const float* __restrict__ IW,
                                                   const float* __restrict__ Ib,
                                                   const float* __restrict__ cemb,
                                                   const float* __restrict__ femb,
                                                   float* __restrict__ tab1,
                                                   float* __restrict__ tab2,
                                                   float* __restrict__ tab3) {
    int blk = blockIdx.x;
    int table = blk / 3072;
    int rem = blk % 3072;
    int row = rem / 12;
    int cc = rem % 12;
    int col = cc * 256 + threadIdx.x;
    int ofs = CND + table * EMBD;
    const float* emb = (table == 1) ? femb : cemb;
    float acc = 0.f;
    for (int k = 0; k < EMBD; ++k)
        acc += emb[row * EMBD + k] * IW[(size_t)(ofs + k) * H3 + col];
    if (table == 0) acc += Ib[col];
    if (table == 2 && ((col & 1023) < 768)) acc = 0.f;
    float* dst = (table == 0) ? tab1 : (table == 1 ? tab2 : tab3);
    dst[(size_t)row * H3 + col] = acc;
}

__global__ __launch_bounds__(256) void build_bfrag2(const float* __restrict__ Rw,
                                                    const float* __restrict__ IW,
                                                    const float* __restrict__ Rb,
                                                    unsigned short* __restrict__ Bf) {
    int idx = blockIdx.x * 256 + threadIdx.x;     // k*3072 + col, k in 0..1119
    int col = idx % 3072;
    int k   = idx / 3072;
    float v;
    if (k < 1024)       v = Rw[(size_t)k * H3 + col];
    else if (k < 1104)  v = IW[(size_t)(k - 1024) * H3 + col];
    else if (k == 1104) v = Rb[col];
    else return;

    int g  = col >> 10;
    int j  = col & 1023;
    int oct = j >> 3, jo = j & 7;
    int which, c;
    if (g < 2)      { which = 0; c = g * 8 + jo; }
    else {
        which = 1;
        if (k < 1024 || k == 1104) c = jo;
        else                        c = 8 + jo;
    }
    int kk = k >> 5, r5 = k & 31;
    int lane = (r5 >> 3) * 16 + c;
    int elem = r5 & 7;
    size_t dst = (((size_t)oct * 2 + which) * 35 + kk) * 512 + lane * 8 + elem;
    __hip_bfloat16 hb = __float2bfloat16(v);
    Bf[dst] = *(unsigned short*)&hb;
}

__global__ __launch_bounds__(256) void build_melA(const float* __restrict__ mel,
                                                  unsigned short* __restrict__ MelA) {
    long idx = (long)blockIdx.x * 256 + threadIdx.x;
    int elem = idx & 7;
    int lane = (idx >> 3) & 63;
    int kkm  = (int)((idx >> 9) % 3);
    int m    = (int)((idx / 1536) & 1);
    int t    = (int)(idx / 3072);
    int b    = m * 16 + (lane & 15);
    int km   = kkm * 32 + ((lane >> 4) & 3) * 8 + elem;
    float v = (km < CND) ? mel[((size_t)b * LEN + t) * CND + km] : (km == CND ? 1.f : 0.f);
    __hip_bfloat16 hb = __float2bfloat16(v);
    MelA[idx] = *(unsigned short*)&hb;
}

__global__ __launch_bounds__(256) void build_wfrag(const float* __restrict__ W,
                                                   unsigned short* __restrict__ Wf,
                                                   int K, int N) {
    int idx = blockIdx.x * 256 + threadIdx.x;
    if (idx >= K * N) return;
    int col = idx % N;
    int k   = idx / N;
    int nt = col >> 4, c = col & 15;
    int kf = k >> 5, k5 = k & 31;
    int lane = c + 16 * (k5 >> 3);
    int elem = k5 & 7;
    size_t dst = ((size_t)nt * (K >> 5) + kf) * 512 + (size_t)lane * 8 + elem;
    __hip_bfloat16 hb = __float2bfloat16(W[idx]);
    Wf[dst] = *(unsigned short*)&hb;
}

// ============================ persistent scan: sentinel dataflow, B in registers ============================
// r13's barrier-free sentinel scheme (measured best: 3.93ms) with ONE change:
// B fragments live in REGISTERS (35 vbf8 = 140 VGPR/wave) instead of LDS.
// At 1 WG/CU x 4 waves, __launch_bounds__(256,1) allows 512 VGPR/wave, so the
// compiler can keep Breg resident (r4-r7's 256-cap provably evicted it).
// This removes ~140 ds_read_b128/CU/step from the LDS port -- the MFMA
// section's binding resource (MfmaUtil 3% => LDS-read-bound, not MFMA-bound).
// LDS drops 141.8KB -> 70.4KB. Everything else r13-verbatim.
__device__ __forceinline__ int is_sent(unsigned long long q) {
    return ((unsigned)q == 0xFFFFFFFFu) || ((unsigned)(q >> 32) == 0xFFFFFFFFu);
}

__global__ __launch_bounds__(256, 1) void scan_persist(const unsigned short* __restrict__ Bf,
                                                       const unsigned short* __restrict__ MelA,
                                                       unsigned short* __restrict__ Af,
                                                       const float* __restrict__ tab1,
                                                       const float* __restrict__ tab2,
                                                       const float* __restrict__ tab3,
                                                       const int* __restrict__ xin) {
    __shared__ __align__(16) unsigned short hstage[64 * 512];     // 65,536 B
    __shared__ float ex[32][36];                                  //  4,608 B

    int tid = threadIdx.x;
    int wg  = blockIdx.x;
    int lane = tid & 63;
    int wv = tid >> 6;            // 0..3
    int m  = wv >> 1;             // A half (batch 0-15 / 16-31)
    int n  = wv & 1;              // 0: [u|r] cols, 1: [e1|e2] cols

    // ---- stationary B fragments -> registers (one-time; 140 VGPR/wave) ----
    vbf8 Breg[35];
    {
        const unsigned short* Bp = Bf + (size_t)wg * (2 * 35 * 512)
                                      + (size_t)n * (35 * 512) + lane * 8;
#pragma unroll
        for (int kk = 0; kk < 35; ++kk)
            Breg[kk] = *(const vbf8*)(Bp + kk * 512);
    }

    // gate role: one (b, j) per thread
    int gb = tid >> 3, gjl = tid & 7;
    int gj = wg * 8 + gjl;
    float hreg = 0.f;
    size_t wbase = (size_t)(((gb >> 4) * 32 + (gj >> 5)) * 512 +
                            ((gb & 15) + 16 * ((gj >> 3) & 3)) * 8 + (gj & 7));

#pragma unroll 1
    for (int t = 0; t < LEN; ++t) {
        // ---- table gathers (cached, hot; issued early, consumed late) ----
        int ci = xin[(gb * LEN + t) * 2];
        int fi = xin[(gb * LEN + t) * 2 + 1];
        int cn = xin[(gb * LEN + ((t + 1) & (LEN - 1))) * 2];
        float t1u = tab1[(size_t)ci * H3 + gj];
        float t2u = tab2[(size_t)fi * H3 + gj];
        float t3u = tab3[(size_t)cn * H3 + gj];
        float t1r = tab1[(size_t)ci * H3 + 1024 + gj];
        float t2r = tab2[(size_t)fi * H3 + 1024 + gj];
        float t3r = tab3[(size_t)cn * H3 + 1024 + gj];
        float t1e = tab1[(size_t)ci * H3 + 2048 + gj];
        float t2e = tab2[(size_t)fi * H3 + 2048 + gj];
        float t3e = tab3[(size_t)cn * H3 + 2048 + gj];

        // ---- pull this wave's 16-frag slice of Af[t] into hstage (u64 atomics) ----
#pragma unroll
        for (int bat = 0; bat < 2; ++bat) {
            int f0 = wv * 16 + bat * 8;
            const unsigned long long* bp =
                (const unsigned long long*)(Af + (size_t)t * 32768 + (size_t)f0 * 512) + lane * 2;
            unsigned long long q[16];
#pragma unroll
            for (int i = 0; i < 8; ++i) {
                q[2 * i]     = __hip_atomic_load(bp + i * 128,     __ATOMIC_RELAXED, __HIP_MEMORY_SCOPE_AGENT);
                q[2 * i + 1] = __hip_atomic_load(bp + i * 128 + 1, __ATOMIC_RELAXED, __HIP_MEMORY_SCOPE_AGENT);
            }
            for (;;) {
                int bad = 0;
#pragma unroll
                for (int i = 0; i < 16; ++i) bad |= is_sent(q[i]);
                if (!__any(bad)) break;
                __builtin_amdgcn_s_sleep(1);
#pragma unroll
                for (int i = 0; i < 8; ++i) {
                    q[2 * i]     = __hip_atomic_load(bp + i * 128,     __ATOMIC_RELAXED, __HIP_MEMORY_SCOPE_AGENT);
                    q[2 * i + 1] = __hip_atomic_load(bp + i * 128 + 1, __ATOMIC_RELAXED, __HIP_MEMORY_SCOPE_AGENT);
                }
            }
#pragma unroll
            for (int i = 0; i < 8; ++i) {
                union { unsigned long long qq[2]; vus8 v; } u;
                u.qq[0] = q[2 * i]; u.qq[1] = q[2 * i + 1];
                *(vus8*)(hstage + (size_t)(f0 + i) * 512 + lane * 8) = u.v;
            }
        }
        __syncthreads();   // hstage complete

        // ---- mel/bias part: A cached, B from registers ----
        const unsigned short* Am = MelA + (size_t)t * 3072 + (size_t)(m * 3) * 512 + lane * 8;
        vf4 acc0 = {0.f, 0.f, 0.f, 0.f}, acc1 = {0.f, 0.f, 0.f, 0.f};
#pragma unroll
        for (int kq = 0; kq < 3; ++kq) {
            vbf8 a = *(const vbf8*)(Am + kq * 512);
            acc0 = __builtin_amdgcn_mfma_f32_16x16x32_bf16(a, Breg[32 + kq], acc0, 0, 0, 0);
        }

        // ---- D(16x16) = A(16x1024) x B: A from LDS, B from registers ----
        const unsigned short* Ah = hstage + (size_t)(m * 32) * 512 + lane * 8;
#pragma unroll
        for (int kk = 0; kk < 32; kk += 2) {
            vbf8 a0v = *(const vbf8*)(Ah + kk * 512);
            acc0 = __builtin_amdgcn_mfma_f32_16x16x32_bf16(a0v, Breg[kk], acc0, 0, 0, 0);
            vbf8 a1v = *(const vbf8*)(Ah + (kk + 1) * 512);
            acc1 = __builtin_amdgcn_mfma_f32_16x16x32_bf16(a1v, Breg[kk + 1], acc1, 0, 0, 0);
        }
        vf4 acc = acc0 + acc1;

        // ---- exchange pre-activations (C: col=lane&15, row=(lane>>4)*4+r) ----
#pragma unroll
        for (int r = 0; r < 4; ++r)
            ex[m * 16 + ((lane >> 4) * 4 + r)][n * 16 + (lane & 15)] = acc[r];
        __syncthreads();

        // ---- gates + state update ----
        float gu  = ex[gb][gjl]      + t1u + t2u + t3u;
        float gr  = ex[gb][8 + gjl]  + t1r + t2r + t3r;
        float e1  = ex[gb][16 + gjl];
        float ge2 = ex[gb][24 + gjl] + t1e + t2e + t3e;
        float u  = 1.f / (1.f + expf(-gu));
        float r_ = 1.f / (1.f + expf(-gr));
        float e  = tanhf(r_ * e1 + ge2);
        hreg = u * hreg + (1.f - u) * e;

        // ---- fire-and-forget packed h store (pair via shfl) ----
        __hip_bfloat16 hb = __float2bfloat16(hreg);
        int myv = (int)(*(unsigned short*)&hb);
        int nbv = __shfl_xor(myv, 1);
        if ((tid & 1) == 0) {
            unsigned int pk = ((unsigned)myv & 0xffffu) | ((unsigned)nbv << 16);
            __hip_atomic_store((unsigned int*)(Af + (size_t)(t + 1) * 32768 + wbase), pk,
                               __ATOMIC_RELAXED, __HIP_MEMORY_SCOPE_AGENT);
        }
        // no drain, no arrival, no fence -- consumers sentinel-poll the data.
    }
}

// ============================ MFMA output MLPs (r12 verbatim) ============================
__global__ __launch_bounds__(512) void out_mlp_mfma(
        const unsigned short* __restrict__ Af,
        const unsigned short* __restrict__ W1f, const float* __restrict__ O1b,
        const unsigned short* __restrict__ W2f, const float* __restrict__ O2b,
        const unsigned short* __restrict__ W3f, const float* __restrict__ O3b,
        const unsigned short* __restrict__ W4f, const float* __restrict__ O4b,
        float* __restrict__ out) {
    __shared__ __align__(16) unsigned short Zc[2 * 24 * 512];   // 48 KB
    __shared__ __align__(16) unsigned short Zf[2 * 8 * 512];    // 16 KB

    int tid = threadIdx.x;
    int lane = tid & 63;
    int wv = tid >> 6;
    int m = wv >> 2;
    int q = wv & 3;
    int l = blockIdx.x;
    int c16 = lane & 15;
    int rowq = lane >> 4;

    const unsigned short* Abase = Af + (size_t)(l + 1) * 32768 +
                                  (size_t)(m * 32) * 512 + (size_t)lane * 8;

    {
        vf4 acc[12];
#pragma unroll
        for (int i = 0; i < 12; ++i) acc[i] = (vf4){0.f, 0.f, 0.f, 0.f};
        for (int kk = 0; kk < 24; ++kk) {
            vbf8 a = *(const vbf8*)(Abase + kk * 512);
#pragma unroll
            for (int i = 0; i < 12; ++i) {
                int nt = q * 12 + i;
                vbf8 b = *(const vbf8*)(W1f + ((size_t)nt * 24 + kk) * 512 + lane * 8);
                acc[i] = __builtin_amdgcn_mfma_f32_16x16x32_bf16(a, b, acc[i], 0, 0, 0);
            }
        }
#pragma unroll
        for (int i = 0; i < 12; ++i) {
            int nt = q * 12 + i;
            int col = nt * 16 + c16;
            float bias = O1b[col];
#pragma unroll
            for (int r = 0; r < 4; ++r) {
                float v = fmaxf(acc[i][r] + bias, 0.f);
                __hip_bfloat16 hb = __float2bfloat16(v);
                int my = (int)*(unsigned short*)&hb;
                int nb = __shfl_xor(my, 1);
                if ((lane & 1) == 0) {
                    unsigned pk = ((unsigned)my & 0xffffu) | ((unsigned)nb << 16);
                    int row = rowq * 4 + r;
                    int kk2 = col >> 5, k5 = col & 31;
                    int lp = row + 16 * (k5 >> 3);
                    int ep = k5 & 7;
                    *(unsigned*)&Zc[(size_t)(m * 24 + kk2) * 512 + lp * 8 + ep] = pk;
                }
            }
        }
    }
    __syncthreads();

    {
        vf4 acc[4];
#pragma unroll
        for (int i = 0; i < 4; ++i) acc[i] = (vf4){0.f, 0.f, 0.f, 0.f};
        for (int kk = 0; kk < 24; ++kk) {
            vbf8 a = *(const vbf8*)(Zc + (size_t)(m * 24 + kk) * 512 + lane * 8);
#pragma unroll
            for (int i = 0; i < 4; ++i) {
                int nt = q * 4 + i;
                vbf8 b = *(const vbf8*)(W2f + ((size_t)nt * 24 + kk) * 512 + lane * 8);
                acc[i] = __builtin_amdgcn_mfma_f32_16x16x32_bf16(a, b, acc[i], 0, 0, 0);
            }
        }
#pragma unroll
        for (int i = 0; i < 4; ++i) {
            int nt = q * 4 + i;
            int col = nt * 16 + c16;
            float bias = O2b[col];
#pragma unroll
            for (int r = 0; r < 4; ++r) {
                int nn = m * 16 + rowq * 4 + r;
                out[((size_t)nn * 1024 + l) * 256 + col] = acc[i][r] + bias;
            }
        }
    }

    {
        vf4 acc[4];
#pragma unroll
        for (int i = 0; i < 4; ++i) acc[i] = (vf4){0.f, 0.f, 0.f, 0.f};
        for (int kf = 0; kf < 8; ++kf) {
            vbf8 a = *(const vbf8*)(Abase + (24 + kf) * 512);
#pragma unroll
            for (int i = 0; i < 4; ++i) {
                int nt = q * 4 + i;
                vbf8 b = *(const vbf8*)(W3f + ((size_t)nt * 8 + kf) * 512 + lane * 8);
                acc[i] = __builtin_amdgcn_mfma_f32_16x16x32_bf16(a, b, acc[i], 0, 0, 0);
            }
        }
#pragma unroll
        for (int i = 0; i < 4; ++i) {
            int nt = q * 4 + i;
            int col = nt * 16 + c16;
            float bias = O3b[col];
#pragma unroll
            for (int r = 0; r < 4; ++r) {
                float v = fmaxf(acc[i][r] + bias, 0.f);
                __hip_bfloat16 hb = __float2bfloat16(v);
                int my = (int)*(unsigned short*)&hb;
                int nb = __shfl_xor(my, 1);
                if ((lane & 1) == 0) {
                    unsigned pk = ((unsigned)my & 0xffffu) | ((unsigned)nb << 16);
                    int row = rowq * 4 + r;
                    int kk2 = col >> 5, k5 = col & 31;
                    int lp = row + 16 * (k5 >> 3);
                    int ep = k5 & 7;
                    *(unsigned*)&Zf[(size_t)(m * 8 + kk2) * 512 + lp * 8 + ep] = pk;
                }
            }
        }
    }
    __syncthreads();

    {
        vf4 acc[4];
#pragma unroll
        for (int i = 0; i < 4; ++i) acc[i] = (vf4){0.f, 0.f, 0.f, 0.f};
        for (int kf = 0; kf < 8; ++kf) {
            vbf8 a = *(const vbf8*)(Zf + (size_t)(m * 8 + kf) * 512 + lane * 8);
#pragma unroll
            for (int i = 0; i < 4; ++i) {
                int nt = q * 4 + i;
                vbf8 b = *(const vbf8*)(W4f + ((size_t)nt * 8 + kf) * 512 + lane * 8);
                acc[i] = __builtin_amdgcn_mfma_f32_16x16x32_bf16(a, b, acc[i], 0, 0, 0);
            }
        }
#pragma unroll
        for (int i = 0; i < 4; ++i) {
            int nt = q * 4 + i;
            int col = nt * 16 + c16;
            float bias = O4b[col];
#pragma unroll
            for (int r = 0; r < 4; ++r) {
                int nn = m * 16 + rowq * 4 + r;
                out[FOFS + ((size_t)nn * 1024 + l) * 256 + col] = acc[i][r] + bias;
            }
        }
    }
}

// ============================ launch ============================
extern "C" void kernel_launch(void* const* d_in, const int* in_sizes, int n_in,
                              void* d_out, int out_size, void* d_ws, size_t ws_size,
                              hipStream_t stream) {
    const int*   x    = (const int*)d_in[0];
    const float* mel  = (const float*)d_in[1];
    const float* Rw   = (const float*)d_in[2];
    const float* Rb   = (const float*)d_in[3];
    const float* IW   = (const float*)d_in[4];
    const float* Ib   = (const float*)d_in[5];
    const float* O1w  = (const float*)d_in[6];
    const float* O1b  = (const float*)d_in[7];
    const float* O2w  = (const float*)d_in[8];
    const float* O2b  = (const float*)d_in[9];
    const float* O3w  = (const float*)d_in[10];
    const float* O3b  = (const float*)d_in[11];
    const float* O4w  = (const float*)d_in[12];
    const float* O4b  = (const float*)d_in[13];
    const float* cemb = (const float*)d_in[14];
    const float* femb = (const float*)d_in[15];
    char* wsb = (char*)d_ws;
    float* out = (float*)d_out;

    float* tab1 = (float*)(wsb + TAB1_B);
    float* tab2 = (float*)(wsb + TAB2_B);
    float* tab3 = (float*)(wsb + TAB3_B);
    unsigned short* Bf   = (unsigned short*)(wsb + BF_B);
    unsigned short* MelA = (unsigned short*)(wsb + MELA_B);
    unsigned short* Af   = (unsigned short*)(wsb + AF_B);
    unsigned short* W1f  = (unsigned short*)(wsb + W1F_B);
    unsigned short* W2f  = (unsigned short*)(wsb + W2F_B);
    unsigned short* W3f  = (unsigned short*)(wsb + W3F_B);
    unsigned short* W4f  = (unsigned short*)(wsb + W4F_B);

    make_tables<<<9216, 256, 0, stream>>>(IW, Ib, cemb, femb, tab1, tab2, tab3);
    hipMemsetAsync((void*)Bf, 0, 4587520ull * 2, stream);
    build_bfrag2<<<13440, 256, 0, stream>>>(Rw, IW, Rb, Bf);
    build_melA<<<12288, 256, 0, stream>>>(mel, MelA);
    build_wfrag<<<2304, 256, 0, stream>>>(O1w, W1f, 768, 768);
    build_wfrag<<<768,  256, 0, stream>>>(O2w, W2f, 768, 256);
    build_wfrag<<<256,  256, 0, stream>>>(O3w, W3f, 256, 256);
    build_wfrag<<<256,  256, 0, stream>>>(O4w, W4f, 256, 256);
    hipMemsetAsync((void*)Af, 0xFF, 33587200ull * 2, stream);   // sentinel-seed all slots
    hipMemsetAsync((void*)Af, 0, 65536, stream);                // h0 = 0 (slot 0 readable)

    scan_persist<<<NWG, NTHR, 0, stream>>>(Bf, MelA, Af, tab1, tab2, tab3, x);

    out_mlp_mfma<<<1024, 512, 0, stream>>>(Af, W1f, O1b, W2f, O2b, W3f, O3b, W4f, O4b, out);
}